// Round 18
// baseline (72.076 us; speedup 1.0000x reference)
//
#include <hip/hip_runtime.h>
#include <math.h>

// Problem constants: B=64, T=2000, V=29, L=200
#define Bn 64
#define Tn 2000
#define Vn 29
#define Ln 200
#define Sn 401              // 2L+1 lattice states
#define BLANKC 28
#define EPSF  1e-7f
#define CHUNK 128           // time steps of linear probs per LDS buffer
#define TSTR  132           // floats per symbol row (128 + pad, quad-aligned)
#define SENT  (-(1 << 20))  // exponent sentinel for all-zero lanes
#define LN2F  0.69314718055994531f

__device__ __forceinline__ float getc(const float4& v, int u) {
    return u == 0 ? v.x : u == 1 ? v.y : u == 2 ? v.z : v.w;
}
// Full-wave DPP shifts: lane i <- lane i-1 (shr) / i+1 (shl); bound_ctrl
// zero-fills the boundary lane. Pure VALU, ~2cyc. (HW-verified R11-R17.)
__device__ __forceinline__ float dpp_shr1_f(float x) {
    return __int_as_float(__builtin_amdgcn_update_dpp(
        0, __float_as_int(x), 0x138, 0xF, 0xF, true));
}
__device__ __forceinline__ int dpp_shr1_i(int x) {
    return __builtin_amdgcn_update_dpp(0, x, 0x138, 0xF, 0xF, true);
}
__device__ __forceinline__ float dpp_shl1_f(float x) {
    return __int_as_float(__builtin_amdgcn_update_dpp(
        0, __float_as_int(x), 0x130, 0xF, 0xF, true));
}
__device__ __forceinline__ int dpp_shl1_i(int x) {
    return __builtin_amdgcn_update_dpp(0, x, 0x130, 0xF, 0xF, true);
}
// 2^d for d in [-126,0]; anything else returns exactly 0 (flush semantics).
__device__ __forceinline__ float dscale(int d) {
    return (d > 0 || d < -126) ? 0.f : __int_as_float((127 + d) << 23);
}

// ================= forward: lane owns states 8l..8l+7 in w[0..7] =================
// 8 DP steps per round; ONE align + renorm per round (BFP, per-lane exponent).
#define ALIGNF_                                                                  \
  const int EeF_ = zf_f ? SENT : E_f;                                            \
  const int EnF_ = max(EeF_, Enb_f);                                             \
  const float snF_ = dscale(EeF_ - EnF_), sbF_ = dscale(Enb_f - EnF_);           \
  float w[8];                                                                    \
  _Pragma("unroll") for (int k = 0; k < 8; ++k) w[k] = a_f[k] * snF_;

#define PREFF8_(POUT0, POUT1, PC, TOFFN)                                         \
  { const int tf_ = (TOFFN) > (CHUNK-8) ? (CHUNK-8) : (TOFFN);                   \
    _Pragma("unroll") for (int m = 0; m < 4; ++m) {                              \
      POUT0[m] = *(const float4*)((PC) + soffF[m] + tf_);                        \
      POUT1[m] = *(const float4*)((PC) + soffF[m] + tf_ + 4); }                  \
    POUT0[4] = *(const float4*)((PC) + BLANKC * TSTR + tf_);                     \
    POUT1[4] = *(const float4*)((PC) + BLANKC * TSTR + tf_ + 4); }

#define STEPF_(PIN, u) {                                                         \
    const float n7_ = dpp_shr1_f(w[7]) * sbF_;                                   \
    const float pb_ = getc(PIN[4], u);                                           \
    w[7] = (fmaf(skF[3], w[5], w[7]) + w[6]) * getc(PIN[3], u);                  \
    w[6] = (w[6] + w[5]) * pb_;                                                  \
    w[5] = (fmaf(skF[2], w[3], w[5]) + w[4]) * getc(PIN[2], u);                  \
    w[4] = (w[4] + w[3]) * pb_;                                                  \
    w[3] = (fmaf(skF[1], w[1], w[3]) + w[2]) * getc(PIN[1], u);                  \
    w[2] = (w[2] + w[1]) * pb_;                                                  \
    w[1] = (fmaf(skF[0], n7_, w[1]) + w[0]) * getc(PIN[0], u);                   \
    w[0] = (w[0] + n7_) * pb_; }

#define FINF_                                                                    \
  float mxF_ = fmaxf(fmaxf(fmaxf(w[0],w[1]),fmaxf(w[2],w[3])),                   \
                     fmaxf(fmaxf(w[4],w[5]),fmaxf(w[6],w[7])));                  \
  const bool zF_ = !(mxF_ > 0.f);                                                \
  const int eF_ = ((__float_as_int(mxF_) >> 23) & 255) - 126;                    \
  const int EnewF_ = EnF_ + eF_;                                                 \
  Enb_f = dpp_shr1_i(zF_ ? SENT : EnewF_);                                       \
  if (lane == 0) Enb_f = SENT;                                                   \
  const float rsF_ = __int_as_float((127 - eF_) << 23);                          \
  _Pragma("unroll") for (int k = 0; k < 8; ++k) a_f[k] = w[k] * rsF_;            \
  E_f = EnewF_; zf_f = zF_;

#define ROUNDF8(T0, PIN0, PIN1, POUT0, POUT1, PC, TOFFN) do {                    \
  ALIGNF_  PREFF8_(POUT0, POUT1, PC, TOFFN)                                      \
  _Pragma("unroll") for (int u = 0; u < 4; ++u) {                                \
    const int t_ = (T0) + u;                                                     \
    if (t_ != 0 && t_ < TFe) STEPF_(PIN0, u)                                     \
  }                                                                              \
  _Pragma("unroll") for (int u = 0; u < 4; ++u) {                                \
    const int t_ = (T0) + 4 + u;                                                 \
    if (t_ != 0 && t_ < TFe) STEPF_(PIN1, u)                                     \
  }                                                                              \
  FINF_                                                                          \
} while (0)

#define ROUNDF8_NG(PIN0, PIN1, POUT0, POUT1, PC, TOFFN) do {                     \
  ALIGNF_  PREFF8_(POUT0, POUT1, PC, TOFFN)                                      \
  STEPF_(PIN0, 0) STEPF_(PIN0, 1) STEPF_(PIN0, 2) STEPF_(PIN0, 3)                \
  STEPF_(PIN1, 0) STEPF_(PIN1, 1) STEPF_(PIN1, 2) STEPF_(PIN1, 3)                \
  FINF_                                                                          \
} while (0)

// ================= backward (beta q-form): lane owns states 8l..8l+7 ============
#define ALIGNB_                                                                  \
  const int EeB_ = zf_b ? SENT : E_b;                                            \
  const int EnB_ = max(EeB_, Enb_b);                                             \
  const float snB_ = dscale(EeB_ - EnB_), sbB_ = dscale(Enb_b - EnB_);           \
  float w[8];                                                                    \
  _Pragma("unroll") for (int k = 0; k < 8; ++k) w[k] = a_b[k] * snB_;

#define PREFB8_(POUT0, POUT1, PC, TOFFN)                                         \
  { const int tf_ = (TOFFN) > (CHUNK-8) ? (CHUNK-8) : (TOFFN);                   \
    _Pragma("unroll") for (int m = 0; m < 4; ++m) {                              \
      POUT0[m] = *(const float4*)((PC) + soffB[m] + tf_);                        \
      POUT1[m] = *(const float4*)((PC) + soffB[m] + tf_ + 4); }                  \
    POUT0[4] = *(const float4*)((PC) + BLANKC * TSTR + tf_);                     \
    POUT1[4] = *(const float4*)((PC) + BLANKC * TSTR + tf_ + 4); }

#define STEPB_(PIN, u) {                                                         \
    const float pb_ = getc(PIN[4], u);                                           \
    const float q0_ = w[0] * pb_;                                                \
    const float q1_ = w[1] * getc(PIN[0], u);                                    \
    const float n8_ = dpp_shl1_f(q0_) * sbB_;                                    \
    const float n9_ = dpp_shl1_f(q1_) * sbB_;                                    \
    const float q2_ = w[2] * pb_;                                                \
    const float q3_ = w[3] * getc(PIN[1], u);                                    \
    const float q4_ = w[4] * pb_;                                                \
    const float q5_ = w[5] * getc(PIN[2], u);                                    \
    const float q6_ = w[6] * pb_;                                                \
    const float q7_ = w[7] * getc(PIN[3], u);                                    \
    w[0] = q0_ + q1_;                                                            \
    w[1] = fmaf(skB[0], q3_, q1_) + q2_;                                         \
    w[2] = q2_ + q3_;                                                            \
    w[3] = fmaf(skB[1], q5_, q3_) + q4_;                                         \
    w[4] = q4_ + q5_;                                                            \
    w[5] = fmaf(skB[2], q7_, q5_) + q6_;                                         \
    w[6] = q6_ + q7_;                                                            \
    w[7] = fmaf(skB[3], n9_, q7_) + n8_; }

#define FINB_                                                                    \
  float mxB_ = fmaxf(fmaxf(fmaxf(w[0],w[1]),fmaxf(w[2],w[3])),                   \
                     fmaxf(fmaxf(w[4],w[5]),fmaxf(w[6],w[7])));                  \
  const bool zB_ = !(mxB_ > 0.f);                                                \
  const int eB_ = ((__float_as_int(mxB_) >> 23) & 255) - 126;                    \
  const int EnewB_ = EnB_ + eB_;                                                 \
  Enb_b = dpp_shl1_i(zB_ ? SENT : EnewB_);                                       \
  if (lane == 63) Enb_b = SENT;                                                  \
  const float rsB_ = __int_as_float((127 - eB_) << 23);                          \
  _Pragma("unroll") for (int k = 0; k < 8; ++k) a_b[k] = w[k] * rsB_;            \
  E_b = EnewB_; zf_b = zB_;

#define ROUNDB8(S0, PIN0, PIN1, POUT0, POUT1, PC, TOFFN) do {                    \
  ALIGNB_  PREFB8_(POUT0, POUT1, PC, TOFFN)                                      \
  _Pragma("unroll") for (int u = 0; u < 4; ++u) {                                \
    const int s_ = (S0) + u;                                                     \
    if (s_ < TBe) STEPB_(PIN0, u)                                                \
  }                                                                              \
  _Pragma("unroll") for (int u = 0; u < 4; ++u) {                                \
    const int s_ = (S0) + 4 + u;                                                 \
    if (s_ < TBe) STEPB_(PIN1, u)                                                \
  }                                                                              \
  FINB_                                                                          \
} while (0)

#define ROUNDB8_NG(PIN0, PIN1, POUT0, POUT1, PC, TOFFN) do {                     \
  ALIGNB_  PREFB8_(POUT0, POUT1, PC, TOFFN)                                      \
  STEPB_(PIN0, 0) STEPB_(PIN0, 1) STEPB_(PIN0, 2) STEPB_(PIN0, 3)                \
  STEPB_(PIN1, 0) STEPB_(PIN1, 1) STEPB_(PIN1, 2) STEPB_(PIN1, 3)                \
  FINB_                                                                          \
} while (0)

__global__ __launch_bounds__(512, 1)
void ctc_pair_kernel(const float* __restrict__ logits,
                     const int*   __restrict__ labels,
                     const int*   __restrict__ input_length,
                     const int*   __restrict__ label_length,
                     const int*   __restrict__ mts_ptr,
                     float*       __restrict__ out)
{
    __shared__ __align__(16) float PFb[2][Vn * TSTR];   // fwd prob dbuf
    __shared__ __align__(16) float PBb[2][Vn * TSTR];   // bwd prob dbuf (time-reversed)

    const int b    = blockIdx.x;
    const int tid  = threadIdx.x;
    const int wid  = tid >> 6;
    // ASYMMETRIC SIMD pairing (wave->SIMD = wid%4, HW-verified R15):
    //   SIMD0: wid0 = fwd DP  +  wid4 = fwd stage   (stage fills DP stalls)
    //   SIMD1: wid1 = bwd DP  +  wid5 = bwd stage
    //   wid2,3,6,7: barrier-only
    const int lane = tid & 63;
    const float* lg  = logits + (size_t)b * Tn * Vn;
    const int*   lab = labels + b * Ln;

    const int mts = *mts_ptr;
    const int ctc_len = (int)floorf((float)(input_length[b] * Tn) / (float)mts);
    const int tend = min(max(ctc_len, 1), Tn);
    const int tm   = (tend - 1) >> 1;      // meeting point
    const int TFe  = tm + 1;               // fwd consumes slots t in [0, TFe)
    const int TBe  = tend - 1 - tm;        // bwd consumes slots i=tend-1-t in [0, TBe)
    const int nchF = (TFe + CHUNK - 1) / CHUNK;
    const int nchB = (TBe + CHUNK - 1) / CHUNK;
    const int nch2 = max(nchF, nchB);

    // ---- fwd metadata: odd states 8l+1..8l+7 -> label rows 4l..4l+3 ----
    int soffF[4]; float skF[4];
    #pragma unroll
    for (int m = 0; m < 4; ++m) {
        const int s = 8 * lane + 2 * m + 1;
        int e = BLANKC; float sk = 0.f;
        if (s < Sn) {
            const int li = (s - 1) >> 1;
            e = lab[li];
            if (s >= 3 && e != lab[li - 1]) sk = 1.f;
        }
        soffF[m] = e * TSTR; skF[m] = sk;
    }
    // ---- bwd metadata ----
    int soffB[4]; float skB[4];
    #pragma unroll
    for (int m = 0; m < 4; ++m) {
        const int s = 8 * lane + 2 * m + 1;
        soffB[m] = ((s < Sn) ? lab[(s - 1) >> 1] : BLANKC) * TSTR;
        const int ssrc = s + 2;
        float sk = 0.f;
        if (ssrc < Sn) {
            const int li = (ssrc - 1) >> 1;
            if (lab[li] != lab[li - 1]) sk = 1.f;
        }
        skB[m] = sk;
    }

    // staging: linear probs (softmax + eps), transposed [v][slot]
    auto srow = [&](const float* row, float* Pb, int i) {
        float x[Vn]; float mm = -INFINITY;
        #pragma unroll
        for (int v = 0; v < Vn; ++v) { x[v] = row[v]; mm = fmaxf(mm, x[v]); }
        float z = 0.f;
        #pragma unroll
        for (int v = 0; v < Vn; ++v) { x[v] = __expf(x[v] - mm); z += x[v]; }
        const float rz = 1.0f / z;
        #pragma unroll
        for (int v = 0; v < Vn; ++v) Pb[v * TSTR + i] = x[v] * rz + EPSF;
    };
    auto stageF = [&](int c) {
        const int base = c * CHUNK;
        const int fill = min(CHUNK, TFe - base);
        float* Pb = PFb[c & 1];
        for (int i = lane; i < fill; i += 64)
            srow(lg + (size_t)(base + i) * Vn, Pb, i);
    };
    auto stageB = [&](int c) {
        const int base = c * CHUNK;
        const int fill = min(CHUNK, TBe - base);
        float* Pb = PBb[c & 1];
        for (int i = lane; i < fill; i += 64)
            srow(lg + (size_t)(tend - 1 - (base + i)) * Vn, Pb, i);
    };

    if (wid == 4) stageF(0);
    if (wid == 5 && TBe > 0) stageB(0);
    __syncthreads();

    // per-lane BFP state
    float a_f[8] = {0.f,0.f,0.f,0.f,0.f,0.f,0.f,0.f};
    float a_b[8] = {0.f,0.f,0.f,0.f,0.f,0.f,0.f,0.f};
    int   E_f = 0, Enb_f = SENT, E_b = 0, Enb_b = SENT;
    bool  zf_f = true, zf_b = true;
    float4 qA0[5], qA1[5], qB0[5], qB1[5];

    if (wid == 0) {
        __builtin_amdgcn_s_setprio(1);
        if (lane == 0) {
            a_f[0] = PFb[0][BLANKC * TSTR];   // alpha0[0]
            a_f[1] = PFb[0][soffF[0]];        // alpha0[1] = p0[lab[0]]
        }
        zf_f = (lane != 0);
        Enb_f = dpp_shr1_i(zf_f ? SENT : 0);
        if (lane == 0) Enb_f = SENT;
    } else if (wid == 1) {
        __builtin_amdgcn_s_setprio(1);
        const int ll = label_length[b];
        const int s1 = 2 * ll, s2 = max(2 * ll - 1, 0);
        #pragma unroll
        for (int k = 0; k < 8; ++k) {
            const int s = 8 * lane + k;
            a_b[k] = (s == s1 || s == s2) ? 0.5f : 0.f;   // beta = 1 (0.5*2^1)
        }
        E_b  = 1;
        zf_b = !(((s1 >> 3) == lane) || ((s2 >> 3) == lane));
        Enb_b = dpp_shl1_i(zf_b ? SENT : E_b);
        if (lane == 63) Enb_b = SENT;
    }

    for (int c = 0; c < nch2; ++c) {
        if (wid == 4) {
            if (c + 1 < nchF) stageF(c + 1);
        } else if (wid == 5) {
            if (c + 1 < nchB) stageB(c + 1);
        } else if (wid == 0) {
            if (c < nchF) {
                float* Pc = PFb[c & 1];
                const int rbase = c * CHUNK;
                const int rcnt  = min(CHUNK, TFe - rbase);
                const int nr    = (rcnt + 7) >> 3;              // 8-step rounds
                const int nfull = min((TFe - rbase) >> 3, nr);  // branchless-safe
                #pragma unroll
                for (int m = 0; m < 4; ++m) {
                    qA0[m] = *(const float4*)(Pc + soffF[m]);
                    qA1[m] = *(const float4*)(Pc + soffF[m] + 4);
                }
                qA0[4] = *(const float4*)(Pc + BLANKC * TSTR);
                qA1[4] = *(const float4*)(Pc + BLANKC * TSTR + 4);

                int jj = 0;
                if (c == 0) {   // first pair guarded (contains t=0)
                    ROUNDF8(0, qA0, qA1, qB0, qB1, Pc, 8);
                    ROUNDF8(8, qB0, qB1, qA0, qA1, Pc, 16);
                    jj = 2;
                }
                for (; jj + 2 <= nfull; jj += 2) {   // hot path: branchless
                    ROUNDF8_NG(qA0, qA1, qB0, qB1, Pc, 8 * (jj + 1));
                    ROUNDF8_NG(qB0, qB1, qA0, qA1, Pc, 8 * (jj + 2));
                }
                for (; jj < nr; jj += 2) {           // tail pair guarded
                    ROUNDF8(rbase + 8 * jj,       qA0, qA1, qB0, qB1, Pc, 8 * (jj + 1));
                    ROUNDF8(rbase + 8 * (jj + 1), qB0, qB1, qA0, qA1, Pc, 8 * (jj + 2));
                }
            }
        } else if (wid == 1) {
            if (c < nchB) {
                float* Pc = PBb[c & 1];
                const int sbase = c * CHUNK;
                const int rcnt  = min(CHUNK, TBe - sbase);
                const int nr    = (rcnt + 7) >> 3;
                const int nfull = min((TBe - sbase) >> 3, nr);
                #pragma unroll
                for (int m = 0; m < 4; ++m) {
                    qA0[m] = *(const float4*)(Pc + soffB[m]);
                    qA1[m] = *(const float4*)(Pc + soffB[m] + 4);
                }
                qA0[4] = *(const float4*)(Pc + BLANKC * TSTR);
                qA1[4] = *(const float4*)(Pc + BLANKC * TSTR + 4);

                int jj = 0;
                for (; jj + 2 <= nfull; jj += 2) {   // hot path: branchless
                    ROUNDB8_NG(qA0, qA1, qB0, qB1, Pc, 8 * (jj + 1));
                    ROUNDB8_NG(qB0, qB1, qA0, qA1, Pc, 8 * (jj + 2));
                }
                for (; jj < nr; jj += 2) {           // tail pair guarded
                    ROUNDB8(sbase + 8 * jj,       qA0, qA1, qB0, qB1, Pc, 8 * (jj + 1));
                    ROUNDB8(sbase + 8 * (jj + 1), qB0, qB1, qA0, qA1, Pc, 8 * (jj + 2));
                }
            }
        }
        __syncthreads();
    }

    // readout: sum_s alpha_tm[s] * beta_tm[s]  (AF/EL alias the prob buffers)
    float* AFa = PFb[0];
    int*   ELa = (int*)(PFb[0] + 512);
    float* AFb = PBb[0];
    int*   ELb = (int*)(PBb[0] + 512);

    if (wid == 0) {
        #pragma unroll
        for (int k = 0; k < 8; ++k) AFa[lane * 8 + k] = a_f[k];
        ELa[lane] = zf_f ? SENT : E_f;
    } else if (wid == 1) {
        #pragma unroll
        for (int k = 0; k < 8; ++k) AFb[lane * 8 + k] = a_b[k];
        ELb[lane] = zf_b ? SENT : E_b;
    }
    __syncthreads();

    if (wid == 0) {
        float v = 0.f;
        #pragma unroll
        for (int k = 0; k < 8; ++k)
            v = fmaf(AFa[lane * 8 + k], AFb[lane * 8 + k], v);
        const int el  = ELa[lane] + ELb[lane];
        const bool val = (v > 0.f);
        int em = val ? el : (SENT * 2);
        #pragma unroll
        for (int off = 1; off < 64; off <<= 1)
            em = max(em, __shfl_xor(em, off, 64));
        float sv = val ? ldexpf(v, el - em) : 0.f;
        #pragma unroll
        for (int off = 1; off < 64; off <<= 1)
            sv += __shfl_xor(sv, off, 64);
        if (lane == 0) out[b] = -(__logf(sv) + (float)em * LN2F);
    }
}

extern "C" void kernel_launch(void* const* d_in, const int* in_sizes, int n_in,
                              void* d_out, int out_size, void* d_ws, size_t ws_size,
                              hipStream_t stream) {
    const float* logits       = (const float*)d_in[0];
    const int*   labels       = (const int*)d_in[1];
    const int*   input_length = (const int*)d_in[2];
    const int*   label_length = (const int*)d_in[3];
    const int*   mts          = (const int*)d_in[4];
    float* out = (float*)d_out;

    ctc_pair_kernel<<<Bn, 512, 0, stream>>>(logits, labels, input_length,
                                            label_length, mts, out);
}

// Round 19
// 67.079 us; speedup vs baseline: 1.0745x; 1.0745x over previous
//
#include <hip/hip_runtime.h>
#include <math.h>

// Problem constants: B=64, T=2000, V=29, L=200
#define Bn 64
#define Tn 2000
#define Vn 29
#define Ln 200
#define Sn 401              // 2L+1 lattice states
#define BLANKC 28
#define EPSF  1e-7f
#define CHUNK 128           // time steps of linear probs per LDS buffer
#define TSTR  132           // floats per symbol row (128 + pad, quad-aligned)
#define SENT  (-(1 << 20))  // exponent sentinel for all-zero lanes
#define LN2F  0.69314718055994531f

__device__ __forceinline__ float getc(const float4& v, int u) {
    return u == 0 ? v.x : u == 1 ? v.y : u == 2 ? v.z : v.w;
}
// Full-wave DPP shifts: lane i <- lane i-1 (shr) / i+1 (shl); bound_ctrl
// zero-fills the boundary lane. Pure VALU, ~2cyc. (HW-verified R11-R18.)
__device__ __forceinline__ float dpp_shr1_f(float x) {
    return __int_as_float(__builtin_amdgcn_update_dpp(
        0, __float_as_int(x), 0x138, 0xF, 0xF, true));
}
__device__ __forceinline__ int dpp_shr1_i(int x) {
    return __builtin_amdgcn_update_dpp(0, x, 0x138, 0xF, 0xF, true);
}
__device__ __forceinline__ float dpp_shl1_f(float x) {
    return __int_as_float(__builtin_amdgcn_update_dpp(
        0, __float_as_int(x), 0x130, 0xF, 0xF, true));
}
__device__ __forceinline__ int dpp_shl1_i(int x) {
    return __builtin_amdgcn_update_dpp(0, x, 0x130, 0xF, 0xF, true);
}
// 2^d for d in [-126,0]; anything else returns exactly 0 (flush semantics).
__device__ __forceinline__ float dscale(int d) {
    return (d > 0 || d < -126) ? 0.f : __int_as_float((127 + d) << 23);
}

// ================= forward: lane owns states 8l..8l+7 in w[0..7] =================
// 16 DP steps per round; ONE align + renorm per round (BFP, per-lane exponent).
#define ALIGNF_                                                                  \
  const int EeF_ = zf_f ? SENT : E_f;                                            \
  const int EnF_ = max(EeF_, Enb_f);                                             \
  const float snF_ = dscale(EeF_ - EnF_), sbF_ = dscale(Enb_f - EnF_);           \
  float w[8];                                                                    \
  _Pragma("unroll") for (int k = 0; k < 8; ++k) w[k] = a_f[k] * snF_;

#define PREFF16_(POUT, PC, TOFFN)                                                \
  { const int tf_ = (TOFFN) > (CHUNK-16) ? (CHUNK-16) : (TOFFN);                 \
    _Pragma("unroll") for (int q = 0; q < 4; ++q) {                              \
      _Pragma("unroll") for (int m = 0; m < 4; ++m)                              \
        POUT[q][m] = *(const float4*)((PC) + soffF[m] + tf_ + 4 * q);            \
      POUT[q][4] = *(const float4*)((PC) + BLANKC * TSTR + tf_ + 4 * q); } }

#define STEPF_(PIN, u) {                                                         \
    const float n7_ = dpp_shr1_f(w[7]) * sbF_;                                   \
    const float pb_ = getc(PIN[4], u);                                           \
    w[7] = (fmaf(skF[3], w[5], w[7]) + w[6]) * getc(PIN[3], u);                  \
    w[6] = (w[6] + w[5]) * pb_;                                                  \
    w[5] = (fmaf(skF[2], w[3], w[5]) + w[4]) * getc(PIN[2], u);                  \
    w[4] = (w[4] + w[3]) * pb_;                                                  \
    w[3] = (fmaf(skF[1], w[1], w[3]) + w[2]) * getc(PIN[1], u);                  \
    w[2] = (w[2] + w[1]) * pb_;                                                  \
    w[1] = (fmaf(skF[0], n7_, w[1]) + w[0]) * getc(PIN[0], u);                   \
    w[0] = (w[0] + n7_) * pb_; }

#define FINF_                                                                    \
  float mxF_ = fmaxf(fmaxf(fmaxf(w[0],w[1]),fmaxf(w[2],w[3])),                   \
                     fmaxf(fmaxf(w[4],w[5]),fmaxf(w[6],w[7])));                  \
  const bool zF_ = !(mxF_ > 0.f);                                                \
  const int eF_ = ((__float_as_int(mxF_) >> 23) & 255) - 126;                    \
  const int EnewF_ = EnF_ + eF_;                                                 \
  Enb_f = dpp_shr1_i(zF_ ? SENT : EnewF_);                                       \
  if (lane == 0) Enb_f = SENT;                                                   \
  const float rsF_ = __int_as_float((127 - eF_) << 23);                          \
  _Pragma("unroll") for (int k = 0; k < 8; ++k) a_f[k] = w[k] * rsF_;            \
  E_f = EnewF_; zf_f = zF_;

#define ROUNDF16(T0, PIN, POUT, PC, TOFFN) do {                                  \
  ALIGNF_  PREFF16_(POUT, PC, TOFFN)                                             \
  _Pragma("unroll") for (int q = 0; q < 4; ++q) {                                \
    _Pragma("unroll") for (int u = 0; u < 4; ++u) {                              \
      const int t_ = (T0) + 4 * q + u;                                           \
      if (t_ != 0 && t_ < TFe) STEPF_(PIN[q], u)                                 \
    } }                                                                          \
  FINF_                                                                          \
} while (0)

#define ROUNDF16_NG(PIN, POUT, PC, TOFFN) do {                                   \
  ALIGNF_  PREFF16_(POUT, PC, TOFFN)                                             \
  STEPF_(PIN[0], 0) STEPF_(PIN[0], 1) STEPF_(PIN[0], 2) STEPF_(PIN[0], 3)        \
  STEPF_(PIN[1], 0) STEPF_(PIN[1], 1) STEPF_(PIN[1], 2) STEPF_(PIN[1], 3)        \
  STEPF_(PIN[2], 0) STEPF_(PIN[2], 1) STEPF_(PIN[2], 2) STEPF_(PIN[2], 3)        \
  STEPF_(PIN[3], 0) STEPF_(PIN[3], 1) STEPF_(PIN[3], 2) STEPF_(PIN[3], 3)        \
  FINF_                                                                          \
} while (0)

// ================= backward (beta q-form): lane owns states 8l..8l+7 ============
#define ALIGNB_                                                                  \
  const int EeB_ = zf_b ? SENT : E_b;                                            \
  const int EnB_ = max(EeB_, Enb_b);                                             \
  const float snB_ = dscale(EeB_ - EnB_), sbB_ = dscale(Enb_b - EnB_);           \
  float w[8];                                                                    \
  _Pragma("unroll") for (int k = 0; k < 8; ++k) w[k] = a_b[k] * snB_;

#define PREFB16_(POUT, PC, TOFFN)                                                \
  { const int tf_ = (TOFFN) > (CHUNK-16) ? (CHUNK-16) : (TOFFN);                 \
    _Pragma("unroll") for (int q = 0; q < 4; ++q) {                              \
      _Pragma("unroll") for (int m = 0; m < 4; ++m)                              \
        POUT[q][m] = *(const float4*)((PC) + soffB[m] + tf_ + 4 * q);            \
      POUT[q][4] = *(const float4*)((PC) + BLANKC * TSTR + tf_ + 4 * q); } }

#define STEPB_(PIN, u) {                                                         \
    const float pb_ = getc(PIN[4], u);                                           \
    const float q0_ = w[0] * pb_;                                                \
    const float q1_ = w[1] * getc(PIN[0], u);                                    \
    const float n8_ = dpp_shl1_f(q0_) * sbB_;                                    \
    const float n9_ = dpp_shl1_f(q1_) * sbB_;                                    \
    const float q2_ = w[2] * pb_;                                                \
    const float q3_ = w[3] * getc(PIN[1], u);                                    \
    const float q4_ = w[4] * pb_;                                                \
    const float q5_ = w[5] * getc(PIN[2], u);                                    \
    const float q6_ = w[6] * pb_;                                                \
    const float q7_ = w[7] * getc(PIN[3], u);                                    \
    w[0] = q0_ + q1_;                                                            \
    w[1] = fmaf(skB[0], q3_, q1_) + q2_;                                         \
    w[2] = q2_ + q3_;                                                            \
    w[3] = fmaf(skB[1], q5_, q3_) + q4_;                                         \
    w[4] = q4_ + q5_;                                                            \
    w[5] = fmaf(skB[2], q7_, q5_) + q6_;                                         \
    w[6] = q6_ + q7_;                                                            \
    w[7] = fmaf(skB[3], n9_, q7_) + n8_; }

#define FINB_                                                                    \
  float mxB_ = fmaxf(fmaxf(fmaxf(w[0],w[1]),fmaxf(w[2],w[3])),                   \
                     fmaxf(fmaxf(w[4],w[5]),fmaxf(w[6],w[7])));                  \
  const bool zB_ = !(mxB_ > 0.f);                                                \
  const int eB_ = ((__float_as_int(mxB_) >> 23) & 255) - 126;                    \
  const int EnewB_ = EnB_ + eB_;                                                 \
  Enb_b = dpp_shl1_i(zB_ ? SENT : EnewB_);                                       \
  if (lane == 63) Enb_b = SENT;                                                  \
  const float rsB_ = __int_as_float((127 - eB_) << 23);                          \
  _Pragma("unroll") for (int k = 0; k < 8; ++k) a_b[k] = w[k] * rsB_;            \
  E_b = EnewB_; zf_b = zB_;

#define ROUNDB16(S0, PIN, POUT, PC, TOFFN) do {                                  \
  ALIGNB_  PREFB16_(POUT, PC, TOFFN)                                             \
  _Pragma("unroll") for (int q = 0; q < 4; ++q) {                                \
    _Pragma("unroll") for (int u = 0; u < 4; ++u) {                              \
      const int s_ = (S0) + 4 * q + u;                                           \
      if (s_ < TBe) STEPB_(PIN[q], u)                                            \
    } }                                                                          \
  FINB_                                                                          \
} while (0)

#define ROUNDB16_NG(PIN, POUT, PC, TOFFN) do {                                   \
  ALIGNB_  PREFB16_(POUT, PC, TOFFN)                                             \
  STEPB_(PIN[0], 0) STEPB_(PIN[0], 1) STEPB_(PIN[0], 2) STEPB_(PIN[0], 3)        \
  STEPB_(PIN[1], 0) STEPB_(PIN[1], 1) STEPB_(PIN[1], 2) STEPB_(PIN[1], 3)        \
  STEPB_(PIN[2], 0) STEPB_(PIN[2], 1) STEPB_(PIN[2], 2) STEPB_(PIN[2], 3)        \
  STEPB_(PIN[3], 0) STEPB_(PIN[3], 1) STEPB_(PIN[3], 2) STEPB_(PIN[3], 3)        \
  FINB_                                                                          \
} while (0)

__global__ __launch_bounds__(256, 1)
void ctc_r16_kernel(const float* __restrict__ logits,
                    const int*   __restrict__ labels,
                    const int*   __restrict__ input_length,
                    const int*   __restrict__ label_length,
                    const int*   __restrict__ mts_ptr,
                    float*       __restrict__ out)
{
    __shared__ __align__(16) float PFb[2][Vn * TSTR];   // fwd prob dbuf
    __shared__ __align__(16) float PBb[2][Vn * TSTR];   // bwd prob dbuf (time-reversed)

    const int b    = blockIdx.x;
    const int tid  = threadIdx.x;
    const int wid  = tid >> 6;    // 0: fwd DP, 1: bwd DP, 2: fwd stage, 3: bwd stage
    const int lane = tid & 63;
    const float* lg  = logits + (size_t)b * Tn * Vn;
    const int*   lab = labels + b * Ln;

    const int mts = *mts_ptr;
    const int ctc_len = (int)floorf((float)(input_length[b] * Tn) / (float)mts);
    const int tend = min(max(ctc_len, 1), Tn);
    const int tm   = (tend - 1) >> 1;      // meeting point
    const int TFe  = tm + 1;               // fwd consumes slots t in [0, TFe)
    const int TBe  = tend - 1 - tm;        // bwd consumes slots i=tend-1-t in [0, TBe)
    const int nchF = (TFe + CHUNK - 1) / CHUNK;
    const int nchB = (TBe + CHUNK - 1) / CHUNK;
    const int nch2 = max(nchF, nchB);

    // ---- fwd metadata: odd states 8l+1..8l+7 -> label rows 4l..4l+3 ----
    int soffF[4]; float skF[4];
    #pragma unroll
    for (int m = 0; m < 4; ++m) {
        const int s = 8 * lane + 2 * m + 1;
        int e = BLANKC; float sk = 0.f;
        if (s < Sn) {
            const int li = (s - 1) >> 1;
            e = lab[li];
            if (s >= 3 && e != lab[li - 1]) sk = 1.f;
        }
        soffF[m] = e * TSTR; skF[m] = sk;
    }
    // ---- bwd metadata ----
    int soffB[4]; float skB[4];
    #pragma unroll
    for (int m = 0; m < 4; ++m) {
        const int s = 8 * lane + 2 * m + 1;
        soffB[m] = ((s < Sn) ? lab[(s - 1) >> 1] : BLANKC) * TSTR;
        const int ssrc = s + 2;
        float sk = 0.f;
        if (ssrc < Sn) {
            const int li = (ssrc - 1) >> 1;
            if (lab[li] != lab[li - 1]) sk = 1.f;
        }
        skB[m] = sk;
    }

    // staging: linear probs (softmax + eps), transposed [v][slot]
    auto srow = [&](const float* row, float* Pb, int i) {
        float x[Vn]; float mm = -INFINITY;
        #pragma unroll
        for (int v = 0; v < Vn; ++v) { x[v] = row[v]; mm = fmaxf(mm, x[v]); }
        float z = 0.f;
        #pragma unroll
        for (int v = 0; v < Vn; ++v) { x[v] = __expf(x[v] - mm); z += x[v]; }
        const float rz = 1.0f / z;
        #pragma unroll
        for (int v = 0; v < Vn; ++v) Pb[v * TSTR + i] = x[v] * rz + EPSF;
    };
    auto stageF = [&](int c) {
        const int base = c * CHUNK;
        const int fill = min(CHUNK, TFe - base);
        float* Pb = PFb[c & 1];
        for (int i = lane; i < fill; i += 64)
            srow(lg + (size_t)(base + i) * Vn, Pb, i);
    };
    auto stageB = [&](int c) {
        const int base = c * CHUNK;
        const int fill = min(CHUNK, TBe - base);
        float* Pb = PBb[c & 1];
        for (int i = lane; i < fill; i += 64)
            srow(lg + (size_t)(tend - 1 - (base + i)) * Vn, Pb, i);
    };

    if (wid == 2) stageF(0);
    if (wid == 3 && TBe > 0) stageB(0);
    __syncthreads();

    // per-lane BFP state
    float a_f[8] = {0.f,0.f,0.f,0.f,0.f,0.f,0.f,0.f};
    float a_b[8] = {0.f,0.f,0.f,0.f,0.f,0.f,0.f,0.f};
    int   E_f = 0, Enb_f = SENT, E_b = 0, Enb_b = SENT;
    bool  zf_f = true, zf_b = true;
    float4 qA[4][5], qB[4][5];   // 16-slot prefetch, A/B rotated

    if (wid == 0) {
        __builtin_amdgcn_s_setprio(1);
        if (lane == 0) {
            a_f[0] = PFb[0][BLANKC * TSTR];   // alpha0[0]
            a_f[1] = PFb[0][soffF[0]];        // alpha0[1] = p0[lab[0]]
        }
        zf_f = (lane != 0);
        Enb_f = dpp_shr1_i(zf_f ? SENT : 0);
        if (lane == 0) Enb_f = SENT;
    } else if (wid == 1) {
        __builtin_amdgcn_s_setprio(1);
        const int ll = label_length[b];
        const int s1 = 2 * ll, s2 = max(2 * ll - 1, 0);
        #pragma unroll
        for (int k = 0; k < 8; ++k) {
            const int s = 8 * lane + k;
            a_b[k] = (s == s1 || s == s2) ? 0.5f : 0.f;   // beta = 1 (0.5*2^1)
        }
        E_b  = 1;
        zf_b = !(((s1 >> 3) == lane) || ((s2 >> 3) == lane));
        Enb_b = dpp_shl1_i(zf_b ? SENT : E_b);
        if (lane == 63) Enb_b = SENT;
    }

    for (int c = 0; c < nch2; ++c) {
        if (wid == 2) {
            if (c + 1 < nchF) stageF(c + 1);
        } else if (wid == 3) {
            if (c + 1 < nchB) stageB(c + 1);
        } else if (wid == 0) {
            if (c < nchF) {
                float* Pc = PFb[c & 1];
                const int rbase = c * CHUNK;
                const int rcnt  = min(CHUNK, TFe - rbase);
                const int nr    = (rcnt + 15) >> 4;             // 16-step rounds
                const int nfull = min((TFe - rbase) >> 4, nr);  // branchless-safe
                #pragma unroll
                for (int q = 0; q < 4; ++q) {
                    #pragma unroll
                    for (int m = 0; m < 4; ++m)
                        qA[q][m] = *(const float4*)(Pc + soffF[m] + 4 * q);
                    qA[q][4] = *(const float4*)(Pc + BLANKC * TSTR + 4 * q);
                }

                int jj = 0;
                if (c == 0) {   // first pair guarded (contains t=0)
                    ROUNDF16(0,  qA, qB, Pc, 16);
                    ROUNDF16(16, qB, qA, Pc, 32);
                    jj = 2;
                }
                for (; jj + 2 <= nfull; jj += 2) {   // hot path: branchless
                    ROUNDF16_NG(qA, qB, Pc, 16 * (jj + 1));
                    ROUNDF16_NG(qB, qA, Pc, 16 * (jj + 2));
                }
                for (; jj < nr; jj += 2) {           // tail pair guarded
                    ROUNDF16(rbase + 16 * jj,       qA, qB, Pc, 16 * (jj + 1));
                    ROUNDF16(rbase + 16 * (jj + 1), qB, qA, Pc, 16 * (jj + 2));
                }
            }
        } else {
            if (c < nchB) {
                float* Pc = PBb[c & 1];
                const int sbase = c * CHUNK;
                const int rcnt  = min(CHUNK, TBe - sbase);
                const int nr    = (rcnt + 15) >> 4;
                const int nfull = min((TBe - sbase) >> 4, nr);
                #pragma unroll
                for (int q = 0; q < 4; ++q) {
                    #pragma unroll
                    for (int m = 0; m < 4; ++m)
                        qA[q][m] = *(const float4*)(Pc + soffB[m] + 4 * q);
                    qA[q][4] = *(const float4*)(Pc + BLANKC * TSTR + 4 * q);
                }

                int jj = 0;
                for (; jj + 2 <= nfull; jj += 2) {   // hot path: branchless
                    ROUNDB16_NG(qA, qB, Pc, 16 * (jj + 1));
                    ROUNDB16_NG(qB, qA, Pc, 16 * (jj + 2));
                }
                for (; jj < nr; jj += 2) {           // tail pair guarded
                    ROUNDB16(sbase + 16 * jj,       qA, qB, Pc, 16 * (jj + 1));
                    ROUNDB16(sbase + 16 * (jj + 1), qB, qA, Pc, 16 * (jj + 2));
                }
            }
        }
        __syncthreads();
    }

    // readout: sum_s alpha_tm[s] * beta_tm[s]  (AF/EL alias the prob buffers)
    float* AFa = PFb[0];
    int*   ELa = (int*)(PFb[0] + 512);
    float* AFb = PBb[0];
    int*   ELb = (int*)(PBb[0] + 512);

    if (wid == 0) {
        #pragma unroll
        for (int k = 0; k < 8; ++k) AFa[lane * 8 + k] = a_f[k];
        ELa[lane] = zf_f ? SENT : E_f;
    } else if (wid == 1) {
        #pragma unroll
        for (int k = 0; k < 8; ++k) AFb[lane * 8 + k] = a_b[k];
        ELb[lane] = zf_b ? SENT : E_b;
    }
    __syncthreads();

    if (wid == 0) {
        float v = 0.f;
        #pragma unroll
        for (int k = 0; k < 8; ++k)
            v = fmaf(AFa[lane * 8 + k], AFb[lane * 8 + k], v);
        const int el  = ELa[lane] + ELb[lane];
        const bool val = (v > 0.f);
        int em = val ? el : (SENT * 2);
        #pragma unroll
        for (int off = 1; off < 64; off <<= 1)
            em = max(em, __shfl_xor(em, off, 64));
        float sv = val ? ldexpf(v, el - em) : 0.f;
        #pragma unroll
        for (int off = 1; off < 64; off <<= 1)
            sv += __shfl_xor(sv, off, 64);
        if (lane == 0) out[b] = -(__logf(sv) + (float)em * LN2F);
    }
}

extern "C" void kernel_launch(void* const* d_in, const int* in_sizes, int n_in,
                              void* d_out, int out_size, void* d_ws, size_t ws_size,
                              hipStream_t stream) {
    const float* logits       = (const float*)d_in[0];
    const int*   labels       = (const int*)d_in[1];
    const int*   input_length = (const int*)d_in[2];
    const int*   label_length = (const int*)d_in[3];
    const int*   mts          = (const int*)d_in[4];
    float* out = (float*)d_out;

    ctc_r16_kernel<<<Bn, 256, 0, stream>>>(logits, labels, input_length,
                                           label_length, mts, out);
}